// Round 12
// baseline (273.212 us; speedup 1.0000x reference)
//
#include <hip/hip_runtime.h>
#include <math.h>

#define NT   16384
#define KD   2048
#define PROJ 256
#define NH   4
#define HD   64
#define NE   64

#define GATES_OFF 0
#define IDX_OFF   (NT * NE)            // 1048576
#define GL_OFF    (NT * NE + NT * 2)   // 1081344

typedef __attribute__((ext_vector_type(8))) short short8;   // 8 bf16 (4 VGPR)
typedef __attribute__((ext_vector_type(4))) float f32x4;    // MFMA C/D

static __device__ __forceinline__ ushort f2bf_rne(float f) {
    uint u = __float_as_uint(f);
    u += 0x7FFFu + ((u >> 16) & 1u);
    return (ushort)(u >> 16);
}
static __device__ __forceinline__ float bf2f(ushort b) {
    return __uint_as_float(((uint)b) << 16);
}

// raw workgroup barrier WITHOUT the __syncthreads vmcnt(0) drain:
// LDS writes must be visible (lgkmcnt(0)); global loads stay in flight.
static __device__ __forceinline__ void barrier_lds_only() {
    asm volatile("s_waitcnt lgkmcnt(0)" ::: "memory");
    __builtin_amdgcn_s_barrier();
    asm volatile("" ::: "memory");     // block hoisting LDS reads above barrier
}

// ---------------------------------------------------------------------------
// K0: split Wp[k][c] (f32) -> transposed bf16 hi/lo WpT_*[c][k], via LDS-tile
// transpose: coalesced reads AND writes. Grid (32,4) tiles of 64k x 64c.
// ---------------------------------------------------------------------------
__global__ __launch_bounds__(256) void k0_split(const float* __restrict__ Wp,
                                                ushort* __restrict__ WpT_hi,
                                                ushort* __restrict__ WpT_lo)
{
    __shared__ ushort Th[64][72];    // [c][k], row stride 144B (16B-aligned)
    __shared__ ushort Tl[64][72];

    const int t  = threadIdx.x;
    const int kb = blockIdx.x * 64;
    const int cb = blockIdx.y * 64;

#pragma unroll
    for (int q = 0; q < 4; ++q) {
        const int s   = t + q * 256;          // 0..1023 float4 slots
        const int row = s >> 4;               // k-row 0..63
        const int c4  = (s & 15) * 4;         // c offset 0..60
        const float4 v = *(const float4*)&Wp[(size_t)(kb + row) * PROJ + cb + c4];
        const float vv[4] = { v.x, v.y, v.z, v.w };
#pragma unroll
        for (int j = 0; j < 4; ++j) {
            const ushort hi = f2bf_rne(vv[j]);
            const ushort lo = f2bf_rne(vv[j] - bf2f(hi));
            Th[c4 + j][row] = hi;
            Tl[c4 + j][row] = lo;
        }
    }
    __syncthreads();

#pragma unroll
    for (int q = 0; q < 2; ++q) {
        const int s    = t + q * 256;         // 0..511 uint4 slots
        const int crow = s >> 3;              // 0..63
        const int kq   = (s & 7) * 8;         // 0..56
        *(uint4*)&WpT_hi[(size_t)(cb + crow) * KD + kb + kq] = *(const uint4*)&Th[crow][kq];
        *(uint4*)&WpT_lo[(size_t)(cb + crow) * KD + kb + kq] = *(const uint4*)&Tl[crow][kq];
    }
}

// ---------------------------------------------------------------------------
// K1: h_T = x @ Wp + bp via bf16 split-3 MFMA.
// Tile 64m x 64n, BK=32, 256 thr = 4 waves (2x2 -> wave-tile 32x32).
// Grid (4 n-blocks, 256 m-blocks) = 1024 blocks = 4 blocks/CU = 16 waves/CU
// (launch_bounds(256,4)) -- 2x R11's TLP; block-local barriers let the 4
// co-resident blocks slip past each other's load stalls. Consecutive
// blockIdx.x share the same 64 x-rows (L2/L3 locality for the 4x re-read).
// A: f32 x -> reg -> trunc-split bf16 hi/lo -> LDS fragment order (16 KB,
//    double-buffered, conflict-free b128); raw lgkmcnt barrier; 2-deep A
//    register prefetch. B: pre-split WpT straight to regs (L2-hot panel).
// 12 MFMA : 4 ds_read_b128 per wave per k-tile.
// ---------------------------------------------------------------------------
__global__ __launch_bounds__(256, 4) void k1_mfma(const float* __restrict__ x,
                                                  const ushort* __restrict__ WpT_hi,
                                                  const ushort* __restrict__ WpT_lo,
                                                  const float* __restrict__ bp,
                                                  float* __restrict__ hT)
{
    __shared__ ushort Ah[2][2048], Al[2][2048];   // 16 KB total

    const int t   = threadIdx.x;
    const int wid = t >> 6;
    const int fm0 = (wid >> 1) * 2;    // wave m-frag base: 0 or 2
    const int wwn = wid & 1;
    const int l   = t & 63;
    const int n0  = blockIdx.x * 64;
    const int m0  = blockIdx.y * 64;

    // A staging: thread t owns slot t: frag f=t>>6, row 16f+(t&15), khalf=(t>>4)&3
    const float* xa = &x[(size_t)(m0 + 16 * (t >> 6) + (t & 15)) * KD + ((t >> 4) & 3) * 8];

    // B fragment base: frag n (0..1) -> col n0 + wwn*32 + n*16 + (l&15)
    const ushort* wph = &WpT_hi[(size_t)(n0 + wwn * 32 + (l & 15)) * KD + (l >> 4) * 8];
    const ushort* wpl = &WpT_lo[(size_t)(n0 + wwn * 32 + (l & 15)) * KD + (l >> 4) * 8];

    f32x4 acc[2][2];
#pragma unroll
    for (int m = 0; m < 2; ++m)
#pragma unroll
        for (int n = 0; n < 2; ++n) acc[m][n] = (f32x4){0.f, 0.f, 0.f, 0.f};

#define K1_STAGE(BUF, PA)                                                      \
    {                                                                          \
        const float ff[8] = { (PA)[0].x, (PA)[0].y, (PA)[0].z, (PA)[0].w,      \
                              (PA)[1].x, (PA)[1].y, (PA)[1].z, (PA)[1].w };    \
        uint hp[4], lp[4];                                                     \
        _Pragma("unroll")                                                      \
        for (int i = 0; i < 4; ++i) {                                          \
            const uint u0 = __float_as_uint(ff[2 * i]);                        \
            const uint u1 = __float_as_uint(ff[2 * i + 1]);                    \
            hp[i] = (u0 >> 16) | (u1 & 0xFFFF0000u);                           \
            const float r0 = ff[2 * i]     - __uint_as_float(u0 & 0xFFFF0000u);\
            const float r1 = ff[2 * i + 1] - __uint_as_float(u1 & 0xFFFF0000u);\
            lp[i] = (__float_as_uint(r0) >> 16) |                              \
                    (__float_as_uint(r1) & 0xFFFF0000u);                       \
        }                                                                      \
        *(uint4*)&Ah[BUF][t * 8] = (uint4){hp[0], hp[1], hp[2], hp[3]};        \
        *(uint4*)&Al[BUF][t * 8] = (uint4){lp[0], lp[1], lp[2], lp[3]};        \
    }

#define K1_LOADA(KB, PA)                                                       \
    PA[0] = *(const float4*)(xa + (KB));                                       \
    PA[1] = *(const float4*)(xa + (KB) + 4);

#define K1_LOADB(KB, BH, BL)                                                   \
    _Pragma("unroll")                                                          \
    for (int n = 0; n < 2; ++n) {                                              \
        BH[n] = *(const short8*)(wph + (size_t)n * 16 * KD + (KB));            \
        BL[n] = *(const short8*)(wpl + (size_t)n * 16 * KD + (KB));            \
    }

#define K1_MFMA(BUF, BH, BL)                                                   \
    _Pragma("unroll")                                                          \
    for (int m = 0; m < 2; ++m) {                                              \
        const short8 ah = *(const short8*)&Ah[BUF][((fm0 + m) * 64 + l) * 8];  \
        const short8 al = *(const short8*)&Al[BUF][((fm0 + m) * 64 + l) * 8];  \
        _Pragma("unroll")                                                      \
        for (int n = 0; n < 2; ++n) {                                          \
            acc[m][n] = __builtin_amdgcn_mfma_f32_16x16x32_bf16(ah, BH[n], acc[m][n], 0, 0, 0); \
            acc[m][n] = __builtin_amdgcn_mfma_f32_16x16x32_bf16(ah, BL[n], acc[m][n], 0, 0, 0); \
            acc[m][n] = __builtin_amdgcn_mfma_f32_16x16x32_bf16(al, BH[n], acc[m][n], 0, 0, 0); \
        }                                                                      \
    }

    float4 A0[2], A1[2];               // 2-deep A prefetch register sets
    short8 bh0[2], bl0[2], bh1[2], bl1[2];

    // ---- prologue: buf0 <- tile0; A1 <- tile1; A0 <- tile2 (in flight)
    K1_LOADA(0, A0);
    K1_LOADA(32, A1);
    K1_LOADB(0, bh0, bl0);
    K1_STAGE(0, A0);                   // counted vmcnt only for A0 here
    K1_LOADA(2 * 32, A0);
    barrier_lds_only();

    for (int tp = 0; tp < 32; ++tp) {
        const int t1 = 2 * tp + 1;
        // ---- even tile 2tp (buf0, B set0)
        K1_LOADB(t1 * 32, bh1, bl1);                 // B for tile t1 (L2-hot)
        K1_MFMA(0, bh0, bl0);
        K1_STAGE(1, A1);                             // stage tile t1
        if (t1 + 2 < 64) { K1_LOADA((t1 + 2) * 32, A1); }
        barrier_lds_only();
        // ---- odd tile 2tp+1 (buf1, B set1)
        if (t1 + 1 < 64) { K1_LOADB((t1 + 1) * 32, bh0, bl0); }
        K1_MFMA(1, bh1, bl1);
        if (t1 + 1 < 64) {
            K1_STAGE(0, A0);                         // stage tile t1+1
            if (t1 + 3 < 64) { K1_LOADA((t1 + 3) * 32, A0); }
            barrier_lds_only();
        }
    }

    // ---- epilogue: bias + channel-major float4 stores (m89 C/D mapping)
#pragma unroll
    for (int n = 0; n < 2; ++n) {
        const int col = n0 + wwn * 32 + n * 16 + (l & 15);
        const float b = bp[col];
#pragma unroll
        for (int m = 0; m < 2; ++m) {
            const int tok = m0 + (fm0 + m) * 16 + (l >> 4) * 4;
            float4 st = { acc[m][n].x + b, acc[m][n].y + b,
                          acc[m][n].z + b, acc[m][n].w + b };
            *(float4*)&hT[(size_t)col * NT + tok] = st;
        }
    }
#undef K1_STAGE
#undef K1_LOADA
#undef K1_LOADB
#undef K1_MFMA
}

// ---------------------------------------------------------------------------
// K2: per head: hid = relu(h @ W1 + b1); hl = hid @ W2 + b2  (both 64x64 GEMMs)
// Channel-major h_T / hl_T. 256 thr, 128 tokens, one head. Per-thread
// 4e x 8tok; W1/W2 in LDS; hid tile through padded LDS; B-frags = global f4.
// ---------------------------------------------------------------------------
__global__ __launch_bounds__(256) void k2_heads(const float* __restrict__ hT,
                                                const float* __restrict__ W1,
                                                const float* __restrict__ b1,
                                                const float* __restrict__ W2,
                                                const float* __restrict__ b2,
                                                float* __restrict__ hlT)
{
    __shared__ float W1s[64][64];
    __shared__ float W2s[64][64];
    __shared__ float Hs[64][132];     // hid tile [d2][tok], pad 132

    const int t    = threadIdx.x;
    const int eg   = t & 15;          // e-group: e = eg*4 + j
    const int tg   = t >> 4;          // tok-group: tok = tok0 + tg*8 + i
    const int head = blockIdx.y;
    const int tok0 = blockIdx.x * 128;

    {   // stage weights (coalesced float4)
        const float4* g1 = (const float4*)(W1 + (size_t)head * HD * HD);
        const float4* g2 = (const float4*)(W2 + (size_t)head * HD * HD);
        float4* s1 = (float4*)&W1s[0][0];
        float4* s2 = (float4*)&W2s[0][0];
#pragma unroll
        for (int q = 0; q < 4; ++q) {
            s1[t + q * 256] = g1[t + q * 256];
            s2[t + q * 256] = g2[t + q * 256];
        }
    }
    const float4 b1v = *(const float4*)&b1[head * HD + eg * 4];
    const float4 b2v = *(const float4*)&b2[head * HD + eg * 4];
    __syncthreads();

    // ---- stage 1: hid[e][tok] = relu(b1 + sum_d h_T[head*64+d][tok]*W1[d][e])
    float acc[4][8];
    {
        const float bb[4] = { b1v.x, b1v.y, b1v.z, b1v.w };
#pragma unroll
        for (int j = 0; j < 4; ++j)
#pragma unroll
            for (int i = 0; i < 8; ++i) acc[j][i] = bb[j];
    }
    const float* hbase = &hT[(size_t)(head * HD) * NT + tok0 + tg * 8];
#pragma unroll 4
    for (int d = 0; d < HD; ++d) {
        const float4 w  = *(const float4*)&W1s[d][eg * 4];
        const float4 h0 = *(const float4*)&hbase[(size_t)d * NT];
        const float4 h1 = *(const float4*)&hbase[(size_t)d * NT + 4];
        const float wv[4] = { w.x, w.y, w.z, w.w };
        const float hv[8] = { h0.x, h0.y, h0.z, h0.w, h1.x, h1.y, h1.z, h1.w };
#pragma unroll
        for (int j = 0; j < 4; ++j)
#pragma unroll
            for (int i = 0; i < 8; ++i)
                acc[j][i] = fmaf(wv[j], hv[i], acc[j][i]);
    }
#pragma unroll
    for (int j = 0; j < 4; ++j) {
        float4 lo, hi;
        lo.x = fmaxf(acc[j][0], 0.f); lo.y = fmaxf(acc[j][1], 0.f);
        lo.z = fmaxf(acc[j][2], 0.f); lo.w = fmaxf(acc[j][3], 0.f);
        hi.x = fmaxf(acc[j][4], 0.f); hi.y = fmaxf(acc[j][5], 0.f);
        hi.z = fmaxf(acc[j][6], 0.f); hi.w = fmaxf(acc[j][7], 0.f);
        *(float4*)&Hs[eg * 4 + j][tg * 8]     = lo;
        *(float4*)&Hs[eg * 4 + j][tg * 8 + 4] = hi;
    }
    __syncthreads();

    // ---- stage 2: hl[e][tok] = b2 + sum_d2 Hs[d2][tok]*W2[d2][e]
    {
        const float bb[4] = { b2v.x, b2v.y, b2v.z, b2v.w };
#pragma unroll
        for (int j = 0; j < 4; ++j)
#pragma unroll
            for (int i = 0; i < 8; ++i) acc[j][i] = bb[j];
    }
#pragma unroll 4
    for (int d = 0; d < HD; ++d) {
        const float4 w  = *(const float4*)&W2s[d][eg * 4];
        const float4 h0 = *(const float4*)&Hs[d][tg * 8];
        const float4 h1 = *(const float4*)&Hs[d][tg * 8 + 4];
        const float wv[4] = { w.x, w.y, w.z, w.w };
        const float hv[8] = { h0.x, h0.y, h0.z, h0.w, h1.x, h1.y, h1.z, h1.w };
#pragma unroll
        for (int j = 0; j < 4; ++j)
#pragma unroll
            for (int i = 0; i < 8; ++i)
                acc[j][i] = fmaf(wv[j], hv[i], acc[j][i]);
    }
#pragma unroll
    for (int j = 0; j < 4; ++j) {
        float4 lo = { acc[j][0], acc[j][1], acc[j][2], acc[j][3] };
        float4 hi = { acc[j][4], acc[j][5], acc[j][6], acc[j][7] };
        float* dst = &hlT[(size_t)(head * HD + eg * 4 + j) * NT + tok0 + tg * 8];
        *(float4*)&dst[0] = lo;
        *(float4*)&dst[4] = hi;
    }
}

// ---------------------------------------------------------------------------
// K3: gl[tok][e] = (hl_T[:, tok] . Wc[:, e] + bc[e]) / clip(T); top-2 softmax.
// 512 thr, 64 tokens/block, per-thread 4e x 2tok. No LDS; Wc L1/L2-resident.
// ---------------------------------------------------------------------------
__global__ __launch_bounds__(512) void k3_gate(const float* __restrict__ hlT,
                                               const float* __restrict__ Wc,
                                               const float* __restrict__ bc,
                                               const float* __restrict__ temp,
                                               float* __restrict__ out)
{
    const int t    = threadIdx.x;
    const int eg   = t & 15;          // e = eg*4 + j  (low lane bits -> shfl ok)
    const int tg   = t >> 4;          // 0..31: tok = tok0 + tg*2 + i
    const int tok0 = blockIdx.x * 64;

    const float tv  = fminf(fmaxf(temp[0], 0.5f), 5.0f);
    const float inv = 1.0f / tv;      // uniform scale: ordering identical to /tv
    const float4 bcv = *(const float4*)&bc[eg * 4];

    float acc[4][2];
    acc[0][0] = bcv.x; acc[0][1] = bcv.x;
    acc[1][0] = bcv.y; acc[1][1] = bcv.y;
    acc[2][0] = bcv.z; acc[2][1] = bcv.z;
    acc[3][0] = bcv.w; acc[3][1] = bcv.w;

    const float* hb = &hlT[tok0 + tg * 2];
#pragma unroll 8
    for (int k = 0; k < PROJ; ++k) {
        const float2 hv = *(const float2*)&hb[(size_t)k * NT];
        const float4 wv = *(const float4*)&Wc[k * NE + eg * 4];
        const float wa[4] = { wv.x, wv.y, wv.z, wv.w };
#pragma unroll
        for (int j = 0; j < 4; ++j) {
            acc[j][0] = fmaf(wa[j], hv.x, acc[j][0]);
            acc[j][1] = fmaf(wa[j], hv.y, acc[j][1]);
        }
    }

#pragma unroll
    for (int i = 0; i < 2; ++i) {
        const int tok = tok0 + tg * 2 + i;
        float gl_[4];
#pragma unroll
        for (int j = 0; j < 4; ++j) gl_[j] = acc[j][i] * inv;

        // top-1 (strict > keeps lowest index; cross-lane ties -> lower index)
        float v1 = gl_[0]; int i1 = eg * 4;
#pragma unroll
        for (int j = 1; j < 4; ++j)
            if (gl_[j] > v1) { v1 = gl_[j]; i1 = eg * 4 + j; }
#pragma unroll
        for (int off = 8; off >= 1; off >>= 1) {
            const float ov = __shfl_xor(v1, off);
            const int   oi = __shfl_xor(i1, off);
            if (ov > v1 || (ov == v1 && oi < i1)) { v1 = ov; i1 = oi; }
        }
        // top-2: exclude winner
        float v2 = -INFINITY; int i2 = NE;
#pragma unroll
        for (int j = 0; j < 4; ++j) {
            const int e = eg * 4 + j;
            if (e != i1 && gl_[j] > v2) { v2 = gl_[j]; i2 = e; }
        }
#pragma unroll
        for (int off = 8; off >= 1; off >>= 1) {
            const float ov = __shfl_xor(v2, off);
            const int   oi = __shfl_xor(i2, off);
            if (ov > v2 || (ov == v2 && oi < i2)) { v2 = ov; i2 = oi; }
        }

        const float e2  = expf(v2 - v1);
        const float s   = 1.f + e2;
        const float g1v = 1.f / s;
        const float g2v = e2 / s;

        float4 gv;
        {
            const int e0 = eg * 4;
            gv.x = (e0 + 0 == i1) ? g1v : ((e0 + 0 == i2) ? g2v : 0.f);
            gv.y = (e0 + 1 == i1) ? g1v : ((e0 + 1 == i2) ? g2v : 0.f);
            gv.z = (e0 + 2 == i1) ? g1v : ((e0 + 2 == i2) ? g2v : 0.f);
            gv.w = (e0 + 3 == i1) ? g1v : ((e0 + 3 == i2) ? g2v : 0.f);
        }
        *(float4*)&out[GATES_OFF + (size_t)tok * NE + eg * 4] = gv;
        const float4 glv = { gl_[0], gl_[1], gl_[2], gl_[3] };
        *(float4*)&out[GL_OFF + (size_t)tok * NE + eg * 4] = glv;
        if (eg == 0) {
            out[IDX_OFF + (size_t)tok * 2 + 0] = (float)i1;
            out[IDX_OFF + (size_t)tok * 2 + 1] = (float)i2;
        }
    }
}

// ---------------------------------------------------------------------------
extern "C" void kernel_launch(void* const* d_in, const int* in_sizes, int n_in,
                              void* d_out, int out_size, void* d_ws, size_t ws_size,
                              hipStream_t stream)
{
    (void)in_sizes; (void)n_in; (void)out_size; (void)ws_size;

    const float* x    = (const float*)d_in[0];
    const float* Wp   = (const float*)d_in[1];
    const float* bp   = (const float*)d_in[2];
    const float* W1   = (const float*)d_in[3];
    const float* b1   = (const float*)d_in[4];
    const float* W2   = (const float*)d_in[5];
    const float* b2   = (const float*)d_in[6];
    const float* Wc   = (const float*)d_in[7];
    const float* bc   = (const float*)d_in[8];
    const float* temp = (const float*)d_in[9];

    float* out = (float*)d_out;
    float* hT  = (float*)d_ws;                    // [256][16384] f32, 16.8 MB
    float* hlT = hT + (size_t)PROJ * NT;          // [256][16384] f32, 16.8 MB

    // Wp bf16 hi/lo splits live in the hlT region (dead until k2 writes it).
    ushort* WpT_hi = (ushort*)hlT;                // 1 MB
    ushort* WpT_lo = WpT_hi + (size_t)KD * PROJ;  // 1 MB

    k0_split<<<dim3(KD / 64, PROJ / 64), 256, 0, stream>>>(Wp, WpT_hi, WpT_lo);
    k1_mfma <<<dim3(PROJ / 64, NT / 64), 256, 0, stream>>>(x, WpT_hi, WpT_lo, bp, hT);
    k2_heads<<<dim3(NT / 128, NH),       256, 0, stream>>>(hT, W1, b1, W2, b2, hlT);
    k3_gate <<<dim3(NT / 64),            512, 0, stream>>>(hlT, Wc, bc, temp, out);
}

// Round 13
// 244.590 us; speedup vs baseline: 1.1170x; 1.1170x over previous
//
#include <hip/hip_runtime.h>
#include <math.h>

#define NT   16384
#define KD   2048
#define PROJ 256
#define NH   4
#define HD   64
#define NE   64

#define GATES_OFF 0
#define IDX_OFF   (NT * NE)            // 1048576
#define GL_OFF    (NT * NE + NT * 2)   // 1081344

typedef __attribute__((ext_vector_type(8))) short short8;   // 8 bf16 (4 VGPR)
typedef __attribute__((ext_vector_type(4))) float f32x4;    // MFMA C/D

static __device__ __forceinline__ ushort f2bf_rne(float f) {
    uint u = __float_as_uint(f);
    u += 0x7FFFu + ((u >> 16) & 1u);
    return (ushort)(u >> 16);
}
static __device__ __forceinline__ float bf2f(ushort b) {
    return __uint_as_float(((uint)b) << 16);
}

// async global -> LDS copy, 16 B per lane (dst = wave-uniform base + lane*16)
static __device__ __forceinline__ void gload16(const void* g, void* s) {
    __builtin_amdgcn_global_load_lds(
        (const __attribute__((address_space(1))) unsigned int*)g,
        (__attribute__((address_space(3))) unsigned int*)s, 16, 0, 0);
}

// in-register truncation split of 8 f32 -> bf16 hi + bf16 lo
static __device__ __forceinline__ void split8(const float4 a, const float4 b,
                                              short8& hi8, short8& lo8)
{
    const float f[8] = { a.x, a.y, a.z, a.w, b.x, b.y, b.z, b.w };
    uint hp[4], lp[4];
#pragma unroll
    for (int i = 0; i < 4; ++i) {
        const uint u0 = __float_as_uint(f[2 * i]);
        const uint u1 = __float_as_uint(f[2 * i + 1]);
        hp[i] = (u0 >> 16) | (u1 & 0xFFFF0000u);
        const float r0 = f[2 * i]     - __uint_as_float(u0 & 0xFFFF0000u);
        const float r1 = f[2 * i + 1] - __uint_as_float(u1 & 0xFFFF0000u);
        lp[i] = (__float_as_uint(r0) >> 16) | (__float_as_uint(r1) & 0xFFFF0000u);
    }
    const uint4 hv = { hp[0], hp[1], hp[2], hp[3] };
    const uint4 lv = { lp[0], lp[1], lp[2], lp[3] };
    hi8 = *(const short8*)&hv;
    lo8 = *(const short8*)&lv;
}

// ---------------------------------------------------------------------------
// K0: split Wp[k][c] (f32) -> transposed bf16 hi/lo WpT_*[c][k], via LDS-tile
// transpose: coalesced reads AND writes. Grid (32,4) tiles of 64k x 64c.
// ---------------------------------------------------------------------------
__global__ __launch_bounds__(256) void k0_split(const float* __restrict__ Wp,
                                                ushort* __restrict__ WpT_hi,
                                                ushort* __restrict__ WpT_lo)
{
    __shared__ ushort Th[64][72];    // [c][k], row stride 144B (16B-aligned)
    __shared__ ushort Tl[64][72];

    const int t  = threadIdx.x;
    const int kb = blockIdx.x * 64;
    const int cb = blockIdx.y * 64;

#pragma unroll
    for (int q = 0; q < 4; ++q) {
        const int s   = t + q * 256;          // 0..1023 float4 slots
        const int row = s >> 4;               // k-row 0..63
        const int c4  = (s & 15) * 4;         // c offset 0..60
        const float4 v = *(const float4*)&Wp[(size_t)(kb + row) * PROJ + cb + c4];
        const float vv[4] = { v.x, v.y, v.z, v.w };
#pragma unroll
        for (int j = 0; j < 4; ++j) {
            const ushort hi = f2bf_rne(vv[j]);
            const ushort lo = f2bf_rne(vv[j] - bf2f(hi));
            Th[c4 + j][row] = hi;
            Tl[c4 + j][row] = lo;
        }
    }
    __syncthreads();

#pragma unroll
    for (int q = 0; q < 2; ++q) {
        const int s    = t + q * 256;         // 0..511 uint4 slots
        const int crow = s >> 3;              // 0..63
        const int kq   = (s & 7) * 8;         // 0..56
        *(uint4*)&WpT_hi[(size_t)(cb + crow) * KD + kb + kq] = *(const uint4*)&Th[crow][kq];
        *(uint4*)&WpT_lo[(size_t)(cb + crow) * KD + kb + kq] = *(const uint4*)&Tl[crow][kq];
    }
}

// ---------------------------------------------------------------------------
// K1: h_T = x @ Wp + bp via bf16 split-3 MFMA, T3-minimum 2-phase schedule.
// Tile 128m x 64n, BK=32, 256 thr = 4 waves (2m x 2n -> wave-tile 64x32).
// Grid (4 n, 128 m) = 512 blocks = 2 blocks/CU. Per k-tile:
//   STAGE(buf^1, t+1): 6x async global_load_lds per thread (A f32 16KB,
//     B hi/lo bf16 4KB+4KB, all in MFMA-fragment order, linear LDS dest)
//   compute(buf): 12 ds_read_b128/wave, in-register trunc-split A, 24 MFMA
//   __syncthreads(): vmcnt(0)+barrier once per tile (drain covered by the
//     full tile of compute; co-resident block fills the residue).
// A slot map: s=(f*64+lane)*2+half <-> row f*16+(lane&15), k (lane>>4)*8+half*4.
// B: wave w stages n-frag w (col n0+w*16+(l&15), k (l>>4)*8).
// ---------------------------------------------------------------------------
__global__ __launch_bounds__(256, 2) void k1_mfma(const float* __restrict__ x,
                                                  const ushort* __restrict__ WpT_hi,
                                                  const ushort* __restrict__ WpT_lo,
                                                  const float* __restrict__ bp,
                                                  float* __restrict__ hT)
{
    __shared__ float  Abuf[2][4096];      // 16 KB x2, A f32 fragment order
    __shared__ ushort Bhbuf[2][2048];     // 4 KB x2
    __shared__ ushort Blbuf[2][2048];     // 4 KB x2

    const int t  = threadIdx.x;
    const int w  = t >> 6;
    const int l  = t & 63;
    const int wm = w >> 1;               // 0..1: m-frags wm*4..+4
    const int wn = w & 1;                // 0..1: n-frags wn*2..+2
    const int n0 = blockIdx.x * 64;
    const int m0 = blockIdx.y * 128;

    // A staging sources: op j of thread t covers slot s=(w*4+j)*64+l
    const float* asrc0;
    const float* asrc1;
    const float* asrc2;
    const float* asrc3;
    {
        const float* tmp[4];
#pragma unroll
        for (int j = 0; j < 4; ++j) {
            const int idx  = w * 4 + j;
            const int f    = idx >> 1;
            const int lf   = ((idx & 1) << 5) | (l >> 1);
            const int half = l & 1;
            const int row  = f * 16 + (lf & 15);
            const int kofs = (lf >> 4) * 8 + half * 4;
            tmp[j] = &x[(size_t)(m0 + row) * KD + kofs];
        }
        asrc0 = tmp[0]; asrc1 = tmp[1]; asrc2 = tmp[2]; asrc3 = tmp[3];
    }
    // B staging sources (wave w stages n-frag w)
    const ushort* bsrc_h = &WpT_hi[(size_t)(n0 + w * 16 + (l & 15)) * KD + (l >> 4) * 8];
    const ushort* bsrc_l = &WpT_lo[(size_t)(n0 + w * 16 + (l & 15)) * KD + (l >> 4) * 8];

    f32x4 acc[4][2];
#pragma unroll
    for (int m = 0; m < 4; ++m)
#pragma unroll
        for (int n = 0; n < 2; ++n) acc[m][n] = (f32x4){0.f, 0.f, 0.f, 0.f};

#define K1_STAGE(BUF, KB)                                                      \
    gload16(asrc0 + (KB), &Abuf[BUF][(w * 4 + 0) * 256]);                      \
    gload16(asrc1 + (KB), &Abuf[BUF][(w * 4 + 1) * 256]);                      \
    gload16(asrc2 + (KB), &Abuf[BUF][(w * 4 + 2) * 256]);                      \
    gload16(asrc3 + (KB), &Abuf[BUF][(w * 4 + 3) * 256]);                      \
    gload16(bsrc_h + (KB), &Bhbuf[BUF][w * 512]);                              \
    gload16(bsrc_l + (KB), &Blbuf[BUF][w * 512]);

#define K1_COMPUTE(BUF)                                                        \
    {                                                                          \
        short8 bh[2], bl[2];                                                   \
        _Pragma("unroll")                                                      \
        for (int n = 0; n < 2; ++n) {                                          \
            const int nf = wn * 2 + n;                                         \
            bh[n] = *(const short8*)&Bhbuf[BUF][(nf * 64 + l) * 8];            \
            bl[n] = *(const short8*)&Blbuf[BUF][(nf * 64 + l) * 8];            \
        }                                                                      \
        _Pragma("unroll")                                                      \
        for (int m = 0; m < 4; ++m) {                                          \
            const int mf = wm * 4 + m;                                         \
            const float4 a0 = *(const float4*)&Abuf[BUF][(mf * 64 + l) * 8];   \
            const float4 a1 = *(const float4*)&Abuf[BUF][(mf * 64 + l) * 8 + 4]; \
            short8 ah, al8;                                                    \
            split8(a0, a1, ah, al8);                                           \
            _Pragma("unroll")                                                  \
            for (int n = 0; n < 2; ++n) {                                      \
                acc[m][n] = __builtin_amdgcn_mfma_f32_16x16x32_bf16(ah, bh[n], acc[m][n], 0, 0, 0); \
                acc[m][n] = __builtin_amdgcn_mfma_f32_16x16x32_bf16(ah, bl[n], acc[m][n], 0, 0, 0); \
                acc[m][n] = __builtin_amdgcn_mfma_f32_16x16x32_bf16(al8, bh[n], acc[m][n], 0, 0, 0); \
            }                                                                  \
        }                                                                      \
    }

    // prologue: stage tile 0, drain, then 2-phase loop
    K1_STAGE(0, 0);
    __syncthreads();

    for (int ti = 0; ti < KD / 32; ++ti) {       // 64 tiles
        const int buf = ti & 1;
        if (ti + 1 < KD / 32) { K1_STAGE(buf ^ 1, (ti + 1) * 32); }
        K1_COMPUTE(buf);
        __syncthreads();                         // vmcnt(0)+barrier once/tile
    }

    // epilogue: bias + channel-major float4 stores (m89 C/D mapping)
#pragma unroll
    for (int n = 0; n < 2; ++n) {
        const int col = n0 + (wn * 2 + n) * 16 + (l & 15);
        const float b = bp[col];
#pragma unroll
        for (int m = 0; m < 4; ++m) {
            const int tok = m0 + (wm * 4 + m) * 16 + (l >> 4) * 4;
            float4 st = { acc[m][n].x + b, acc[m][n].y + b,
                          acc[m][n].z + b, acc[m][n].w + b };
            *(float4*)&hT[(size_t)col * NT + tok] = st;
        }
    }
#undef K1_STAGE
#undef K1_COMPUTE
}

// ---------------------------------------------------------------------------
// K2: per head: hid = relu(h @ W1 + b1); hl = hid @ W2 + b2  (both 64x64 GEMMs)
// Channel-major h_T / hl_T. 256 thr, 128 tokens, one head. Per-thread
// 4e x 8tok; W1/W2 in LDS; hid tile through padded LDS; B-frags = global f4.
// ---------------------------------------------------------------------------
__global__ __launch_bounds__(256) void k2_heads(const float* __restrict__ hT,
                                                const float* __restrict__ W1,
                                                const float* __restrict__ b1,
                                                const float* __restrict__ W2,
                                                const float* __restrict__ b2,
                                                float* __restrict__ hlT)
{
    __shared__ float W1s[64][64];
    __shared__ float W2s[64][64];
    __shared__ float Hs[64][132];     // hid tile [d2][tok], pad 132

    const int t    = threadIdx.x;
    const int eg   = t & 15;          // e-group: e = eg*4 + j
    const int tg   = t >> 4;          // tok-group: tok = tok0 + tg*8 + i
    const int head = blockIdx.y;
    const int tok0 = blockIdx.x * 128;

    {   // stage weights (coalesced float4)
        const float4* g1 = (const float4*)(W1 + (size_t)head * HD * HD);
        const float4* g2 = (const float4*)(W2 + (size_t)head * HD * HD);
        float4* s1 = (float4*)&W1s[0][0];
        float4* s2 = (float4*)&W2s[0][0];
#pragma unroll
        for (int q = 0; q < 4; ++q) {
            s1[t + q * 256] = g1[t + q * 256];
            s2[t + q * 256] = g2[t + q * 256];
        }
    }
    const float4 b1v = *(const float4*)&b1[head * HD + eg * 4];
    const float4 b2v = *(const float4*)&b2[head * HD + eg * 4];
    __syncthreads();

    // ---- stage 1: hid[e][tok] = relu(b1 + sum_d h_T[head*64+d][tok]*W1[d][e])
    float acc[4][8];
    {
        const float bb[4] = { b1v.x, b1v.y, b1v.z, b1v.w };
#pragma unroll
        for (int j = 0; j < 4; ++j)
#pragma unroll
            for (int i = 0; i < 8; ++i) acc[j][i] = bb[j];
    }
    const float* hbase = &hT[(size_t)(head * HD) * NT + tok0 + tg * 8];
#pragma unroll 4
    for (int d = 0; d < HD; ++d) {
        const float4 w  = *(const float4*)&W1s[d][eg * 4];
        const float4 h0 = *(const float4*)&hbase[(size_t)d * NT];
        const float4 h1 = *(const float4*)&hbase[(size_t)d * NT + 4];
        const float wv[4] = { w.x, w.y, w.z, w.w };
        const float hv[8] = { h0.x, h0.y, h0.z, h0.w, h1.x, h1.y, h1.z, h1.w };
#pragma unroll
        for (int j = 0; j < 4; ++j)
#pragma unroll
            for (int i = 0; i < 8; ++i)
                acc[j][i] = fmaf(wv[j], hv[i], acc[j][i]);
    }
#pragma unroll
    for (int j = 0; j < 4; ++j) {
        float4 lo, hi;
        lo.x = fmaxf(acc[j][0], 0.f); lo.y = fmaxf(acc[j][1], 0.f);
        lo.z = fmaxf(acc[j][2], 0.f); lo.w = fmaxf(acc[j][3], 0.f);
        hi.x = fmaxf(acc[j][4], 0.f); hi.y = fmaxf(acc[j][5], 0.f);
        hi.z = fmaxf(acc[j][6], 0.f); hi.w = fmaxf(acc[j][7], 0.f);
        *(float4*)&Hs[eg * 4 + j][tg * 8]     = lo;
        *(float4*)&Hs[eg * 4 + j][tg * 8 + 4] = hi;
    }
    __syncthreads();

    // ---- stage 2: hl[e][tok] = b2 + sum_d2 Hs[d2][tok]*W2[d2][e]
    {
        const float bb[4] = { b2v.x, b2v.y, b2v.z, b2v.w };
#pragma unroll
        for (int j = 0; j < 4; ++j)
#pragma unroll
            for (int i = 0; i < 8; ++i) acc[j][i] = bb[j];
    }
#pragma unroll 4
    for (int d = 0; d < HD; ++d) {
        const float4 w  = *(const float4*)&W2s[d][eg * 4];
        const float4 h0 = *(const float4*)&Hs[d][tg * 8];
        const float4 h1 = *(const float4*)&Hs[d][tg * 8 + 4];
        const float wv[4] = { w.x, w.y, w.z, w.w };
        const float hv[8] = { h0.x, h0.y, h0.z, h0.w, h1.x, h1.y, h1.z, h1.w };
#pragma unroll
        for (int j = 0; j < 4; ++j)
#pragma unroll
            for (int i = 0; i < 8; ++i)
                acc[j][i] = fmaf(wv[j], hv[i], acc[j][i]);
    }
#pragma unroll
    for (int j = 0; j < 4; ++j) {
        float4 lo = { acc[j][0], acc[j][1], acc[j][2], acc[j][3] };
        float4 hi = { acc[j][4], acc[j][5], acc[j][6], acc[j][7] };
        float* dst = &hlT[(size_t)(head * HD + eg * 4 + j) * NT + tok0 + tg * 8];
        *(float4*)&dst[0] = lo;
        *(float4*)&dst[4] = hi;
    }
}

// ---------------------------------------------------------------------------
// K3: gl[tok][e] = (hl_T[:, tok] . Wc[:, e] + bc[e]) / clip(T); top-2 softmax.
// 512 thr, 64 tokens/block, per-thread 4e x 2tok. No LDS; Wc L1/L2-resident.
// ---------------------------------------------------------------------------
__global__ __launch_bounds__(512) void k3_gate(const float* __restrict__ hlT,
                                               const float* __restrict__ Wc,
                                               const float* __restrict__ bc,
                                               const float* __restrict__ temp,
                                               float* __restrict__ out)
{
    const int t    = threadIdx.x;
    const int eg   = t & 15;          // e = eg*4 + j  (low lane bits -> shfl ok)
    const int tg   = t >> 4;          // 0..31: tok = tok0 + tg*2 + i
    const int tok0 = blockIdx.x * 64;

    const float tv  = fminf(fmaxf(temp[0], 0.5f), 5.0f);
    const float inv = 1.0f / tv;      // uniform scale: ordering identical to /tv
    const float4 bcv = *(const float4*)&bc[eg * 4];

    float acc[4][2];
    acc[0][0] = bcv.x; acc[0][1] = bcv.x;
    acc[1][0] = bcv.y; acc[1][1] = bcv.y;
    acc[2][0] = bcv.z; acc[2][1] = bcv.z;
    acc[3][0] = bcv.w; acc[3][1] = bcv.w;

    const float* hb = &hlT[tok0 + tg * 2];
#pragma unroll 8
    for (int k = 0; k < PROJ; ++k) {
        const float2 hv = *(const float2*)&hb[(size_t)k * NT];
        const float4 wv = *(const float4*)&Wc[k * NE + eg * 4];
        const float wa[4] = { wv.x, wv.y, wv.z, wv.w };
#pragma unroll
        for (int j = 0; j < 4; ++j) {
            acc[j][0] = fmaf(wa[j], hv.x, acc[j][0]);
            acc[j][1] = fmaf(wa[j], hv.y, acc[j][1]);
        }
    }

#pragma unroll
    for (int i = 0; i < 2; ++i) {
        const int tok = tok0 + tg * 2 + i;
        float gl_[4];
#pragma unroll
        for (int j = 0; j < 4; ++j) gl_[j] = acc[j][i] * inv;

        // top-1 (strict > keeps lowest index; cross-lane ties -> lower index)
        float v1 = gl_[0]; int i1 = eg * 4;
#pragma unroll
        for (int j = 1; j < 4; ++j)
            if (gl_[j] > v1) { v1 = gl_[j]; i1 = eg * 4 + j; }
#pragma unroll
        for (int off = 8; off >= 1; off >>= 1) {
            const float ov = __shfl_xor(v1, off);
            const int   oi = __shfl_xor(i1, off);
            if (ov > v1 || (ov == v1 && oi < i1)) { v1 = ov; i1 = oi; }
        }
        // top-2: exclude winner
        float v2 = -INFINITY; int i2 = NE;
#pragma unroll
        for (int j = 0; j < 4; ++j) {
            const int e = eg * 4 + j;
            if (e != i1 && gl_[j] > v2) { v2 = gl_[j]; i2 = e; }
        }
#pragma unroll
        for (int off = 8; off >= 1; off >>= 1) {
            const float ov = __shfl_xor(v2, off);
            const int   oi = __shfl_xor(i2, off);
            if (ov > v2 || (ov == v2 && oi < i2)) { v2 = ov; i2 = oi; }
        }

        const float e2  = expf(v2 - v1);
        const float s   = 1.f + e2;
        const float g1v = 1.f / s;
        const float g2v = e2 / s;

        float4 gv;
        {
            const int e0 = eg * 4;
            gv.x = (e0 + 0 == i1) ? g1v : ((e0 + 0 == i2) ? g2v : 0.f);
            gv.y = (e0 + 1 == i1) ? g1v : ((e0 + 1 == i2) ? g2v : 0.f);
            gv.z = (e0 + 2 == i1) ? g1v : ((e0 + 2 == i2) ? g2v : 0.f);
            gv.w = (e0 + 3 == i1) ? g1v : ((e0 + 3 == i2) ? g2v : 0.f);
        }
        *(float4*)&out[GATES_OFF + (size_t)tok * NE + eg * 4] = gv;
        const float4 glv = { gl_[0], gl_[1], gl_[2], gl_[3] };
        *(float4*)&out[GL_OFF + (size_t)tok * NE + eg * 4] = glv;
        if (eg == 0) {
            out[IDX_OFF + (size_t)tok * 2 + 0] = (float)i1;
            out[IDX_OFF + (size_t)tok * 2 + 1] = (float)i2;
        }
    }
}

// ---------------------------------------------------------------------------
extern "C" void kernel_launch(void* const* d_in, const int* in_sizes, int n_in,
                              void* d_out, int out_size, void* d_ws, size_t ws_size,
                              hipStream_t stream)
{
    (void)in_sizes; (void)n_in; (void)out_size; (void)ws_size;

    const float* x    = (const float*)d_in[0];
    const float* Wp   = (const float*)d_in[1];
    const float* bp   = (const float*)d_in[2];
    const float* W1   = (const float*)d_in[3];
    const float* b1   = (const float*)d_in[4];
    const float* W2   = (const float*)d_in[5];
    const float* b2   = (const float*)d_in[6];
    const float* Wc   = (const float*)d_in[7];
    const float* bc   = (const float*)d_in[8];
    const float* temp = (const float*)d_in[9];

    float* out = (float*)d_out;
    float* hT  = (float*)d_ws;                    // [256][16384] f32, 16.8 MB
    float* hlT = hT + (size_t)PROJ * NT;          // [256][16384] f32, 16.8 MB

    // Wp bf16 hi/lo splits live in the hlT region (dead until k2 writes it).
    ushort* WpT_hi = (ushort*)hlT;                // 1 MB
    ushort* WpT_lo = WpT_hi + (size_t)KD * PROJ;  // 1 MB

    k0_split<<<dim3(KD / 64, PROJ / 64), 256, 0, stream>>>(Wp, WpT_hi, WpT_lo);
    k1_mfma <<<dim3(PROJ / 64, NT / 128), 256, 0, stream>>>(x, WpT_hi, WpT_lo, bp, hT);
    k2_heads<<<dim3(NT / 128, NH),        256, 0, stream>>>(hT, W1, b1, W2, b2, hlT);
    k3_gate <<<dim3(NT / 64),             512, 0, stream>>>(hlT, Wc, bc, temp, out);
}

// Round 14
// 209.926 us; speedup vs baseline: 1.3015x; 1.1651x over previous
//
#include <hip/hip_runtime.h>
#include <math.h>

#define NT   16384
#define KD   2048
#define PROJ 256
#define NH   4
#define HD   64
#define NE   64

#define GATES_OFF 0
#define IDX_OFF   (NT * NE)            // 1048576
#define GL_OFF    (NT * NE + NT * 2)   // 1081344

typedef __attribute__((ext_vector_type(8))) short short8;   // 8 bf16 (4 VGPR)
typedef __attribute__((ext_vector_type(4))) float f32x4;    // MFMA C/D

static __device__ __forceinline__ ushort f2bf_rne(float f) {
    uint u = __float_as_uint(f);
    u += 0x7FFFu + ((u >> 16) & 1u);
    return (ushort)(u >> 16);
}
static __device__ __forceinline__ float bf2f(ushort b) {
    return __uint_as_float(((uint)b) << 16);
}

// async global -> LDS copy, 16 B per lane (dst = wave-uniform base + lane*16)
static __device__ __forceinline__ void gload16(const void* g, void* s) {
    __builtin_amdgcn_global_load_lds(
        (const __attribute__((address_space(1))) unsigned int*)g,
        (__attribute__((address_space(3))) unsigned int*)s, 16, 0, 0);
}

// in-register truncation split of 8 f32 -> bf16 hi + bf16 lo
static __device__ __forceinline__ void split8(const float4 a, const float4 b,
                                              short8& hi8, short8& lo8)
{
    const float f[8] = { a.x, a.y, a.z, a.w, b.x, b.y, b.z, b.w };
    uint hp[4], lp[4];
#pragma unroll
    for (int i = 0; i < 4; ++i) {
        const uint u0 = __float_as_uint(f[2 * i]);
        const uint u1 = __float_as_uint(f[2 * i + 1]);
        hp[i] = (u0 >> 16) | (u1 & 0xFFFF0000u);
        const float r0 = f[2 * i]     - __uint_as_float(u0 & 0xFFFF0000u);
        const float r1 = f[2 * i + 1] - __uint_as_float(u1 & 0xFFFF0000u);
        lp[i] = (__float_as_uint(r0) >> 16) | (__float_as_uint(r1) & 0xFFFF0000u);
    }
    const uint4 hv = { hp[0], hp[1], hp[2], hp[3] };
    const uint4 lv = { lp[0], lp[1], lp[2], lp[3] };
    hi8 = *(const short8*)&hv;
    lo8 = *(const short8*)&lv;
}

// ---------------------------------------------------------------------------
// K0: split Wp[k][c] (f32) -> transposed bf16 hi/lo WpT_*[c][k], via LDS-tile
// transpose: coalesced reads AND writes.
// ---------------------------------------------------------------------------
__global__ __launch_bounds__(256) void k0_split(const float* __restrict__ Wp,
                                                ushort* __restrict__ WpT_hi,
                                                ushort* __restrict__ WpT_lo)
{
    __shared__ ushort Th[64][72];
    __shared__ ushort Tl[64][72];

    const int t  = threadIdx.x;
    const int kb = blockIdx.x * 64;
    const int cb = blockIdx.y * 64;

#pragma unroll
    for (int q = 0; q < 4; ++q) {
        const int s   = t + q * 256;
        const int row = s >> 4;
        const int c4  = (s & 15) * 4;
        const float4 v = *(const float4*)&Wp[(size_t)(kb + row) * PROJ + cb + c4];
        const float vv[4] = { v.x, v.y, v.z, v.w };
#pragma unroll
        for (int j = 0; j < 4; ++j) {
            const ushort hi = f2bf_rne(vv[j]);
            const ushort lo = f2bf_rne(vv[j] - bf2f(hi));
            Th[c4 + j][row] = hi;
            Tl[c4 + j][row] = lo;
        }
    }
    __syncthreads();

#pragma unroll
    for (int q = 0; q < 2; ++q) {
        const int s    = t + q * 256;
        const int crow = s >> 3;
        const int kq   = (s & 7) * 8;
        *(uint4*)&WpT_hi[(size_t)(cb + crow) * KD + kb + kq] = *(const uint4*)&Th[crow][kq];
        *(uint4*)&WpT_lo[(size_t)(cb + crow) * KD + kb + kq] = *(const uint4*)&Tl[crow][kq];
    }
}

// ---------------------------------------------------------------------------
// K0c: W2c[h] = W2[h] @ Wc[h*64:(h+1)*64]  (64x64 each), and bias partials
// bcpart[h][e] = sum_d b2[h][d] * Wc[h*64+d][e]. Exact fold (f32):
// gate_logits = sum_h hid_h @ W2c_h + (bc + sum_h bcpart[h]).
// ---------------------------------------------------------------------------
__global__ __launch_bounds__(256) void k0c(const float* __restrict__ W2,
                                           const float* __restrict__ Wc,
                                           const float* __restrict__ b2,
                                           float* __restrict__ W2c,
                                           float* __restrict__ bcpart)
{
    __shared__ float W2sT[64][65];   // [d2][d]  (transposed W2, pad 65)
    __shared__ float Wcs[64][64];    // [d2][e]

    const int t    = threadIdx.x;
    const int head = blockIdx.x;

    {   // stage Wc rows head*64.. (contiguous) as float4
        const float4* gc = (const float4*)(Wc + (size_t)head * 64 * NE);
        float4* sc = (float4*)&Wcs[0][0];
#pragma unroll
        for (int q = 0; q < 4; ++q) sc[t + q * 256] = gc[t + q * 256];
    }
    {   // stage W2[head] transposed: read f4 rows, scatter scalar
        const float* g2 = W2 + (size_t)head * HD * HD;
#pragma unroll
        for (int q = 0; q < 4; ++q) {
            const int s = t + q * 256;       // 0..1023 float4 slots
            const int r = s >> 4;            // d row
            const int c = (s & 15) * 4;      // d2 col
            const float4 v = *(const float4*)&g2[r * HD + c];
            W2sT[c + 0][r] = v.x; W2sT[c + 1][r] = v.y;
            W2sT[c + 2][r] = v.z; W2sT[c + 3][r] = v.w;
        }
    }
    __syncthreads();

    const int eg = t & 15;     // e = eg*4 + j
    const int dg = t >> 4;     // d = dg*4 + i
    float acc[4][4];
#pragma unroll
    for (int i = 0; i < 4; ++i)
#pragma unroll
        for (int j = 0; j < 4; ++j) acc[i][j] = 0.f;

    for (int d2 = 0; d2 < 64; ++d2) {
        const float4 wc = *(const float4*)&Wcs[d2][eg * 4];
        const float4 w2 = *(const float4*)&W2sT[d2][dg * 4];
        const float wcv[4] = { wc.x, wc.y, wc.z, wc.w };
        const float w2v[4] = { w2.x, w2.y, w2.z, w2.w };
#pragma unroll
        for (int i = 0; i < 4; ++i)
#pragma unroll
            for (int j = 0; j < 4; ++j)
                acc[i][j] = fmaf(w2v[i], wcv[j], acc[i][j]);
    }
#pragma unroll
    for (int i = 0; i < 4; ++i) {
        float4 v = { acc[i][0], acc[i][1], acc[i][2], acc[i][3] };
        *(float4*)&W2c[(size_t)head * 4096 + (dg * 4 + i) * 64 + eg * 4] = v;
    }

    if (t < 64) {   // bias partial for this head
        float p = 0.f;
        for (int d = 0; d < 64; ++d)
            p = fmaf(b2[head * HD + d], Wcs[d][t], p);
        bcpart[head * NE + t] = p;
    }
}

// ---------------------------------------------------------------------------
// K1: h_T = x @ Wp + bp via bf16 split-3 MFMA, T3 2-phase schedule with
// COALESCED global_load_lds staging + XOR-swizzled LDS granules (T2/T21):
//   A (f32 128x32 tile): granule(row,kg) at phys row*8 + (kg^(row&7));
//     stage: lane idx -> row=idx>>3, kg=(idx&7)^(row&7) -> 128B-chunk
//     coalesced global reads, LINEAR LDS dest. Fragment b128 reads hit 8
//     distinct bank-quads per 8 lanes (conflict-free). Split to bf16 hi/lo
//     in registers at read time.
//   B (bf16 hi/lo 64x32): granule(c,ko) at phys c*4 + (ko^(c&3)); 64B-chunk
//     coalesced stage; <=2-way (free) on fragment reads.
// Tile 128m x 64n, BK=32, 4 waves (2m x 2n), grid (4,128)=512 = 2 blocks/CU.
// Per wave per tile: 12 ds_read_b128 : 24 MFMA; one __syncthreads per tile.
// ---------------------------------------------------------------------------
__global__ __launch_bounds__(256, 2) void k1_mfma(const float* __restrict__ x,
                                                  const ushort* __restrict__ WpT_hi,
                                                  const ushort* __restrict__ WpT_lo,
                                                  const float* __restrict__ bp,
                                                  float* __restrict__ hT)
{
    __shared__ float  Abuf[2][4096];      // 16 KB x2
    __shared__ ushort Bhbuf[2][2048];     // 4 KB x2
    __shared__ ushort Blbuf[2][2048];     // 4 KB x2

    const int t  = threadIdx.x;
    const int w  = t >> 6;
    const int l  = t & 63;
    const int wm = w >> 1;               // m-frags wm*4 .. +4
    const int wn = w & 1;                // n-frags wn*2 .. +2
    const int n0 = blockIdx.x * 64;
    const int m0 = blockIdx.y * 128;

    // ---- A staging sources (coalesced, inverse-swizzled granule)
    // op p covers granules p*256 + t: row = p*32 + (t>>3), kg = (t&7)^(row&7)
    const float* asrc0; const float* asrc1;
    const float* asrc2; const float* asrc3;
    {
        const float* tmp[4];
#pragma unroll
        for (int p = 0; p < 4; ++p) {
            const int row = p * 32 + (t >> 3);
            const int kg  = (t & 7) ^ (row & 7);
            tmp[p] = &x[(size_t)(m0 + row) * KD + kg * 4];
        }
        asrc0 = tmp[0]; asrc1 = tmp[1]; asrc2 = tmp[2]; asrc3 = tmp[3];
    }
    // ---- B staging sources: granule t: c = t>>2, ko = (t&3)^(c&3)
    const int bc_  = t >> 2;
    const int bko  = (t & 3) ^ (bc_ & 3);
    const ushort* bsrch = &WpT_hi[(size_t)(n0 + bc_) * KD + bko * 8];
    const ushort* bsrcl = &WpT_lo[(size_t)(n0 + bc_) * KD + bko * 8];

    f32x4 acc[4][2];
#pragma unroll
    for (int m = 0; m < 4; ++m)
#pragma unroll
        for (int n = 0; n < 2; ++n) acc[m][n] = (f32x4){0.f, 0.f, 0.f, 0.f};

#define K1_STAGE(BUF, KB)                                                      \
    gload16(asrc0 + (KB), &Abuf[BUF][(0 * 256 + w * 64) * 4]);                 \
    gload16(asrc1 + (KB), &Abuf[BUF][(1 * 256 + w * 64) * 4]);                 \
    gload16(asrc2 + (KB), &Abuf[BUF][(2 * 256 + w * 64) * 4]);                 \
    gload16(asrc3 + (KB), &Abuf[BUF][(3 * 256 + w * 64) * 4]);                 \
    gload16(bsrch + (KB), &Bhbuf[BUF][w * 512]);                               \
    gload16(bsrcl + (KB), &Blbuf[BUF][w * 512]);

#define K1_COMPUTE(BUF)                                                        \
    {                                                                          \
        short8 bh[2], bl[2];                                                   \
        _Pragma("unroll")                                                      \
        for (int n = 0; n < 2; ++n) {                                          \
            const int c  = (wn * 2 + n) * 16 + (l & 15);                       \
            const int ph = c * 4 + ((l >> 4) ^ (c & 3));                       \
            bh[n] = *(const short8*)&Bhbuf[BUF][ph * 8];                       \
            bl[n] = *(const short8*)&Blbuf[BUF][ph * 8];                       \
        }                                                                      \
        _Pragma("unroll")                                                      \
        for (int m = 0; m < 4; ++m) {                                          \
            const int row = (wm * 4 + m) * 16 + (l & 15);                      \
            const int p0  = row * 8 + (((l >> 4) * 2 + 0) ^ (row & 7));        \
            const int p1  = row * 8 + (((l >> 4) * 2 + 1) ^ (row & 7));        \
            const float4 a0 = *(const float4*)&Abuf[BUF][p0 * 4];              \
            const float4 a1 = *(const float4*)&Abuf[BUF][p1 * 4];              \
            short8 ah, al8;                                                    \
            split8(a0, a1, ah, al8);                                           \
            _Pragma("unroll")                                                  \
            for (int n = 0; n < 2; ++n) {                                      \
                acc[m][n] = __builtin_amdgcn_mfma_f32_16x16x32_bf16(ah,  bh[n], acc[m][n], 0, 0, 0); \
                acc[m][n] = __builtin_amdgcn_mfma_f32_16x16x32_bf16(ah,  bl[n], acc[m][n], 0, 0, 0); \
                acc[m][n] = __builtin_amdgcn_mfma_f32_16x16x32_bf16(al8, bh[n], acc[m][n], 0, 0, 0); \
            }                                                                  \
        }                                                                      \
    }

    K1_STAGE(0, 0);
    __syncthreads();

    for (int ti = 0; ti < KD / 32; ++ti) {       // 64 tiles
        const int buf = ti & 1;
        if (ti + 1 < KD / 32) { K1_STAGE(buf ^ 1, (ti + 1) * 32); }
        K1_COMPUTE(buf);
        __syncthreads();
    }

    // epilogue: bias + channel-major float4 stores (m89 C/D mapping)
#pragma unroll
    for (int n = 0; n < 2; ++n) {
        const int col = n0 + (wn * 2 + n) * 16 + (l & 15);
        const float b = bp[col];
#pragma unroll
        for (int m = 0; m < 4; ++m) {
            const int tok = m0 + (wm * 4 + m) * 16 + (l >> 4) * 4;
            float4 st = { acc[m][n].x + b, acc[m][n].y + b,
                          acc[m][n].z + b, acc[m][n].w + b };
            *(float4*)&hT[(size_t)col * NT + tok] = st;
        }
    }
#undef K1_STAGE
#undef K1_COMPUTE
}

// ---------------------------------------------------------------------------
// K23: fused per-head MLP + gate. Per block: 128 tokens.
//   accg = bc + sum_h bcpart[h]                  (exact fold bias)
//   for head: hid = relu(h_h @ W1_h + b1_h); accg += hid @ W2c_h
//   gl = accg / clip(T); top-2 + softmax; write gates/idx/gl.
// hlT never materialized. 256 thr; per-thread 4e x 8tok.
// ---------------------------------------------------------------------------
__global__ __launch_bounds__(256) void k23_gate(const float* __restrict__ hT,
                                                const float* __restrict__ W1,
                                                const float* __restrict__ b1,
                                                const float* __restrict__ W2c,
                                                const float* __restrict__ bcpart,
                                                const float* __restrict__ bc,
                                                const float* __restrict__ temp,
                                                float* __restrict__ out)
{
    __shared__ float W1s[64][64];
    __shared__ float W2cs[64][64];
    __shared__ float Hs[64][132];

    const int t    = threadIdx.x;
    const int eg   = t & 15;          // e = eg*4 + j
    const int tg   = t >> 4;          // tok = tok0 + tg*8 + i
    const int tok0 = blockIdx.x * 128;

    const float tv  = fminf(fmaxf(temp[0], 0.5f), 5.0f);
    const float inv = 1.0f / tv;

    float accg[4][8];
    {
        float bcp[4];
#pragma unroll
        for (int j = 0; j < 4; ++j) {
            const int e = eg * 4 + j;
            bcp[j] = bc[e] + bcpart[e] + bcpart[NE + e]
                   + bcpart[2 * NE + e] + bcpart[3 * NE + e];
        }
#pragma unroll
        for (int j = 0; j < 4; ++j)
#pragma unroll
            for (int i = 0; i < 8; ++i) accg[j][i] = bcp[j];
    }

    for (int head = 0; head < NH; ++head) {
        __syncthreads();   // prior head's W2cs/Hs reads complete
        {   // stage W1[head], W2c[head]
            const float4* g1 = (const float4*)(W1 + (size_t)head * HD * HD);
            const float4* g2 = (const float4*)(W2c + (size_t)head * HD * HD);
            float4* s1 = (float4*)&W1s[0][0];
            float4* s2 = (float4*)&W2cs[0][0];
#pragma unroll
            for (int q = 0; q < 4; ++q) {
                s1[t + q * 256] = g1[t + q * 256];
                s2[t + q * 256] = g2[t + q * 256];
            }
        }
        const float4 b1v = *(const float4*)&b1[head * HD + eg * 4];
        __syncthreads();

        // stage 1: hid = relu(b1 + h @ W1)
        float acc[4][8];
        {
            const float bb[4] = { b1v.x, b1v.y, b1v.z, b1v.w };
#pragma unroll
            for (int j = 0; j < 4; ++j)
#pragma unroll
                for (int i = 0; i < 8; ++i) acc[j][i] = bb[j];
        }
        const float* hbase = &hT[(size_t)(head * HD) * NT + tok0 + tg * 8];
#pragma unroll 4
        for (int d = 0; d < HD; ++d) {
            const float4 w  = *(const float4*)&W1s[d][eg * 4];
            const float4 h0 = *(const float4*)&hbase[(size_t)d * NT];
            const float4 h1 = *(const float4*)&hbase[(size_t)d * NT + 4];
            const float wv[4] = { w.x, w.y, w.z, w.w };
            const float hv[8] = { h0.x, h0.y, h0.z, h0.w, h1.x, h1.y, h1.z, h1.w };
#pragma unroll
            for (int j = 0; j < 4; ++j)
#pragma unroll
                for (int i = 0; i < 8; ++i)
                    acc[j][i] = fmaf(wv[j], hv[i], acc[j][i]);
        }
#pragma unroll
        for (int j = 0; j < 4; ++j) {
            float4 lo, hi;
            lo.x = fmaxf(acc[j][0], 0.f); lo.y = fmaxf(acc[j][1], 0.f);
            lo.z = fmaxf(acc[j][2], 0.f); lo.w = fmaxf(acc[j][3], 0.f);
            hi.x = fmaxf(acc[j][4], 0.f); hi.y = fmaxf(acc[j][5], 0.f);
            hi.z = fmaxf(acc[j][6], 0.f); hi.w = fmaxf(acc[j][7], 0.f);
            *(float4*)&Hs[eg * 4 + j][tg * 8]     = lo;
            *(float4*)&Hs[eg * 4 + j][tg * 8 + 4] = hi;
        }
        __syncthreads();

        // stage 2: accg += Hs @ W2c[head]
#pragma unroll 4
        for (int d = 0; d < HD; ++d) {
            const float4 w  = *(const float4*)&W2cs[d][eg * 4];
            const float4 h0 = *(const float4*)&Hs[d][tg * 8];
            const float4 h1 = *(const float4*)&Hs[d][tg * 8 + 4];
            const float wv[4] = { w.x, w.y, w.z, w.w };
            const float hv[8] = { h0.x, h0.y, h0.z, h0.w, h1.x, h1.y, h1.z, h1.w };
#pragma unroll
            for (int j = 0; j < 4; ++j)
#pragma unroll
                for (int i = 0; i < 8; ++i)
                    accg[j][i] = fmaf(wv[j], hv[i], accg[j][i]);
        }
    }

    // top-2 + softmax + outputs, per token i
#pragma unroll
    for (int i = 0; i < 8; ++i) {
        const int tok = tok0 + tg * 8 + i;
        float gl_[4];
#pragma unroll
        for (int j = 0; j < 4; ++j) gl_[j] = accg[j][i] * inv;

        float v1 = gl_[0]; int i1 = eg * 4;
#pragma unroll
        for (int j = 1; j < 4; ++j)
            if (gl_[j] > v1) { v1 = gl_[j]; i1 = eg * 4 + j; }
#pragma unroll
        for (int off = 8; off >= 1; off >>= 1) {
            const float ov = __shfl_xor(v1, off);
            const int   oi = __shfl_xor(i1, off);
            if (ov > v1 || (ov == v1 && oi < i1)) { v1 = ov; i1 = oi; }
        }
        float v2 = -INFINITY; int i2 = NE;
#pragma unroll
        for (int j = 0; j < 4; ++j) {
            const int e = eg * 4 + j;
            if (e != i1 && gl_[j] > v2) { v2 = gl_[j]; i2 = e; }
        }
#pragma unroll
        for (int off = 8; off >= 1; off >>= 1) {
            const float ov = __shfl_xor(v2, off);
            const int   oi = __shfl_xor(i2, off);
            if (ov > v2 || (ov == v2 && oi < i2)) { v2 = ov; i2 = oi; }
        }

        const float e2  = expf(v2 - v1);
        const float s   = 1.f + e2;
        const float g1v = 1.f / s;
        const float g2v = e2 / s;

        float4 gv;
        {
            const int e0 = eg * 4;
            gv.x = (e0 + 0 == i1) ? g1v : ((e0 + 0 == i2) ? g2v : 0.f);
            gv.y = (e0 + 1 == i1) ? g1v : ((e0 + 1 == i2) ? g2v : 0.f);
            gv.z = (e0 + 2 == i1) ? g1v : ((e0 + 2 == i2) ? g2v : 0.f);
            gv.w = (e0 + 3 == i1) ? g1v : ((e0 + 3 == i2) ? g2v : 0.f);
        }
        *(float4*)&out[GATES_OFF + (size_t)tok * NE + eg * 4] = gv;
        const float4 glv = { gl_[0], gl_[1], gl_[2], gl_[3] };
        *(float4*)&out[GL_OFF + (size_t)tok * NE + eg * 4] = glv;
        if (eg == 0) {
            out[IDX_OFF + (size_t)tok * 2 + 0] = (float)i1;
            out[IDX_OFF + (size_t)tok * 2 + 1] = (float)i2;
        }
    }
}

// ---------------------------------------------------------------------------
extern "C" void kernel_launch(void* const* d_in, const int* in_sizes, int n_in,
                              void* d_out, int out_size, void* d_ws, size_t ws_size,
                              hipStream_t stream)
{
    (void)in_sizes; (void)n_in; (void)out_size; (void)ws_size;

    const float* x    = (const float*)d_in[0];
    const float* Wp   = (const float*)d_in[1];
    const float* bp   = (const float*)d_in[2];
    const float* W1   = (const float*)d_in[3];
    const float* b1   = (const float*)d_in[4];
    const float* W2   = (const float*)d_in[5];
    const float* b2   = (const float*)d_in[6];
    const float* Wc   = (const float*)d_in[7];
    const float* bc   = (const float*)d_in[8];
    const float* temp = (const float*)d_in[9];

    float* out = (float*)d_out;
    float* hT  = (float*)d_ws;                         // 16.8 MB
    ushort* WpT_hi = (ushort*)(hT + (size_t)PROJ * NT); // 1 MB
    ushort* WpT_lo = WpT_hi + (size_t)KD * PROJ;        // 1 MB
    float*  W2c    = (float*)(WpT_lo + (size_t)KD * PROJ); // 64 KB
    float*  bcpart = W2c + NH * HD * NE;                // 1 KB

    k0_split<<<dim3(KD / 64, PROJ / 64), 256, 0, stream>>>(Wp, WpT_hi, WpT_lo);
    k0c     <<<dim3(NH),                 256, 0, stream>>>(W2, Wc, b2, W2c, bcpart);
    k1_mfma <<<dim3(PROJ / 64, NT / 128), 256, 0, stream>>>(x, WpT_hi, WpT_lo, bp, hT);
    k23_gate<<<dim3(NT / 128),           256, 0, stream>>>(hT, W1, b1, W2c, bcpart, bc, temp, out);
}

// Round 15
// 209.399 us; speedup vs baseline: 1.3047x; 1.0025x over previous
//
#include <hip/hip_runtime.h>
#include <math.h>

#define NT   16384
#define KD   2048
#define PROJ 256
#define NH   4
#define HD   64
#define NE   64

#define GATES_OFF 0
#define IDX_OFF   (NT * NE)            // 1048576
#define GL_OFF    (NT * NE + NT * 2)   // 1081344

typedef __attribute__((ext_vector_type(8))) short short8;   // 8 bf16 (4 VGPR)
typedef __attribute__((ext_vector_type(4))) float f32x4;    // MFMA C/D

static __device__ __forceinline__ ushort f2bf_rne(float f) {
    uint u = __float_as_uint(f);
    u += 0x7FFFu + ((u >> 16) & 1u);
    return (ushort)(u >> 16);
}
static __device__ __forceinline__ float bf2f(ushort b) {
    return __uint_as_float(((uint)b) << 16);
}

// async global -> LDS copy, 16 B per lane (dst = wave-uniform base + lane*16)
static __device__ __forceinline__ void gload16(const void* g, void* s) {
    __builtin_amdgcn_global_load_lds(
        (const __attribute__((address_space(1))) unsigned int*)g,
        (__attribute__((address_space(3))) unsigned int*)s, 16, 0, 0);
}

// in-register truncation split of 8 f32 -> bf16 hi + bf16 lo
static __device__ __forceinline__ void split8(const float4 a, const float4 b,
                                              short8& hi8, short8& lo8)
{
    const float f[8] = { a.x, a.y, a.z, a.w, b.x, b.y, b.z, b.w };
    uint hp[4], lp[4];
#pragma unroll
    for (int i = 0; i < 4; ++i) {
        const uint u0 = __float_as_uint(f[2 * i]);
        const uint u1 = __float_as_uint(f[2 * i + 1]);
        hp[i] = (u0 >> 16) | (u1 & 0xFFFF0000u);
        const float r0 = f[2 * i]     - __uint_as_float(u0 & 0xFFFF0000u);
        const float r1 = f[2 * i + 1] - __uint_as_float(u1 & 0xFFFF0000u);
        lp[i] = (__float_as_uint(r0) >> 16) | (__float_as_uint(r1) & 0xFFFF0000u);
    }
    const uint4 hv = { hp[0], hp[1], hp[2], hp[3] };
    const uint4 lv = { lp[0], lp[1], lp[2], lp[3] };
    hi8 = *(const short8*)&hv;
    lo8 = *(const short8*)&lv;
}

// ---------------------------------------------------------------------------
// K0: split Wp[k][c] (f32) -> transposed bf16 hi/lo WpT_*[c][k], via LDS-tile
// transpose: coalesced reads AND writes.
// ---------------------------------------------------------------------------
__global__ __launch_bounds__(256) void k0_split(const float* __restrict__ Wp,
                                                ushort* __restrict__ WpT_hi,
                                                ushort* __restrict__ WpT_lo)
{
    __shared__ ushort Th[64][72];
    __shared__ ushort Tl[64][72];

    const int t  = threadIdx.x;
    const int kb = blockIdx.x * 64;
    const int cb = blockIdx.y * 64;

#pragma unroll
    for (int q = 0; q < 4; ++q) {
        const int s   = t + q * 256;
        const int row = s >> 4;
        const int c4  = (s & 15) * 4;
        const float4 v = *(const float4*)&Wp[(size_t)(kb + row) * PROJ + cb + c4];
        const float vv[4] = { v.x, v.y, v.z, v.w };
#pragma unroll
        for (int j = 0; j < 4; ++j) {
            const ushort hi = f2bf_rne(vv[j]);
            const ushort lo = f2bf_rne(vv[j] - bf2f(hi));
            Th[c4 + j][row] = hi;
            Tl[c4 + j][row] = lo;
        }
    }
    __syncthreads();

#pragma unroll
    for (int q = 0; q < 2; ++q) {
        const int s    = t + q * 256;
        const int crow = s >> 3;
        const int kq   = (s & 7) * 8;
        *(uint4*)&WpT_hi[(size_t)(cb + crow) * KD + kb + kq] = *(const uint4*)&Th[crow][kq];
        *(uint4*)&WpT_lo[(size_t)(cb + crow) * KD + kb + kq] = *(const uint4*)&Tl[crow][kq];
    }
}

// ---------------------------------------------------------------------------
// K0c: W2c[h] = W2[h] @ Wc[h*64:(h+1)*64]  (64x64 each), and bias partials
// bcpart[h][e] = sum_d b2[h][d] * Wc[h*64+d][e]. Exact fold (f32):
// gate_logits = sum_h hid_h @ W2c_h + (bc + sum_h bcpart[h]).
// ---------------------------------------------------------------------------
__global__ __launch_bounds__(256) void k0c(const float* __restrict__ W2,
                                           const float* __restrict__ Wc,
                                           const float* __restrict__ b2,
                                           float* __restrict__ W2c,
                                           float* __restrict__ bcpart)
{
    __shared__ float W2sT[64][65];   // [d2][d]  (transposed W2, pad 65)
    __shared__ float Wcs[64][64];    // [d2][e]

    const int t    = threadIdx.x;
    const int head = blockIdx.x;

    {   // stage Wc rows head*64.. (contiguous) as float4
        const float4* gc = (const float4*)(Wc + (size_t)head * 64 * NE);
        float4* sc = (float4*)&Wcs[0][0];
#pragma unroll
        for (int q = 0; q < 4; ++q) sc[t + q * 256] = gc[t + q * 256];
    }
    {   // stage W2[head] transposed: read f4 rows, scatter scalar
        const float* g2 = W2 + (size_t)head * HD * HD;
#pragma unroll
        for (int q = 0; q < 4; ++q) {
            const int s = t + q * 256;       // 0..1023 float4 slots
            const int r = s >> 4;            // d row
            const int c = (s & 15) * 4;      // d2 col
            const float4 v = *(const float4*)&g2[r * HD + c];
            W2sT[c + 0][r] = v.x; W2sT[c + 1][r] = v.y;
            W2sT[c + 2][r] = v.z; W2sT[c + 3][r] = v.w;
        }
    }
    __syncthreads();

    const int eg = t & 15;     // e = eg*4 + j
    const int dg = t >> 4;     // d = dg*4 + i
    float acc[4][4];
#pragma unroll
    for (int i = 0; i < 4; ++i)
#pragma unroll
        for (int j = 0; j < 4; ++j) acc[i][j] = 0.f;

    for (int d2 = 0; d2 < 64; ++d2) {
        const float4 wc = *(const float4*)&Wcs[d2][eg * 4];
        const float4 w2 = *(const float4*)&W2sT[d2][dg * 4];
        const float wcv[4] = { wc.x, wc.y, wc.z, wc.w };
        const float w2v[4] = { w2.x, w2.y, w2.z, w2.w };
#pragma unroll
        for (int i = 0; i < 4; ++i)
#pragma unroll
            for (int j = 0; j < 4; ++j)
                acc[i][j] = fmaf(w2v[i], wcv[j], acc[i][j]);
    }
#pragma unroll
    for (int i = 0; i < 4; ++i) {
        float4 v = { acc[i][0], acc[i][1], acc[i][2], acc[i][3] };
        *(float4*)&W2c[(size_t)head * 4096 + (dg * 4 + i) * 64 + eg * 4] = v;
    }

    if (t < 64) {   // bias partial for this head
        float p = 0.f;
        for (int d = 0; d < 64; ++d)
            p = fmaf(b2[head * HD + d], Wcs[d][t], p);
        bcpart[head * NE + t] = p;
    }
}

// ---------------------------------------------------------------------------
// K1: h_T = x @ Wp + bp via bf16 split-3 MFMA, T3 2-phase schedule with
// COALESCED global_load_lds staging + XOR-swizzled LDS granules (T2/T21):
//   A (f32 128x32 tile): granule(row,kg) at phys row*8 + (kg^(row&7));
//     stage: lane idx -> row=idx>>3, kg=(idx&7)^(row&7) -> 128B-chunk
//     coalesced global reads, LINEAR LDS dest. Fragment b128 reads hit 8
//     distinct bank-quads per 8 lanes (conflict-free). Split to bf16 hi/lo
//     in registers at read time.
//   B (bf16 hi/lo 64x32): granule(c,ko) at phys c*4 + (ko^(c&3)); 64B-chunk
//     coalesced stage; <=2-way (free) on fragment reads.
// Tile 128m x 64n, BK=32, 4 waves (2m x 2n), grid (4,128)=512 = 2 blocks/CU.
// Per wave per tile: 12 ds_read_b128 : 24 MFMA; one __syncthreads per tile.
// ---------------------------------------------------------------------------
__global__ __launch_bounds__(256, 2) void k1_mfma(const float* __restrict__ x,
                                                  const ushort* __restrict__ WpT_hi,
                                                  const ushort* __restrict__ WpT_lo,
                                                  const float* __restrict__ bp,
                                                  float* __restrict__ hT)
{
    __shared__ float  Abuf[2][4096];      // 16 KB x2
    __shared__ ushort Bhbuf[2][2048];     // 4 KB x2
    __shared__ ushort Blbuf[2][2048];     // 4 KB x2

    const int t  = threadIdx.x;
    const int w  = t >> 6;
    const int l  = t & 63;
    const int wm = w >> 1;               // m-frags wm*4 .. +4
    const int wn = w & 1;                // n-frags wn*2 .. +2
    const int n0 = blockIdx.x * 64;
    const int m0 = blockIdx.y * 128;

    // ---- A staging sources (coalesced, inverse-swizzled granule)
    // op p covers granules p*256 + t: row = p*32 + (t>>3), kg = (t&7)^(row&7)
    const float* asrc0; const float* asrc1;
    const float* asrc2; const float* asrc3;
    {
        const float* tmp[4];
#pragma unroll
        for (int p = 0; p < 4; ++p) {
            const int row = p * 32 + (t >> 3);
            const int kg  = (t & 7) ^ (row & 7);
            tmp[p] = &x[(size_t)(m0 + row) * KD + kg * 4];
        }
        asrc0 = tmp[0]; asrc1 = tmp[1]; asrc2 = tmp[2]; asrc3 = tmp[3];
    }
    // ---- B staging sources: granule t: c = t>>2, ko = (t&3)^(c&3)
    const int bc_  = t >> 2;
    const int bko  = (t & 3) ^ (bc_ & 3);
    const ushort* bsrch = &WpT_hi[(size_t)(n0 + bc_) * KD + bko * 8];
    const ushort* bsrcl = &WpT_lo[(size_t)(n0 + bc_) * KD + bko * 8];

    f32x4 acc[4][2];
#pragma unroll
    for (int m = 0; m < 4; ++m)
#pragma unroll
        for (int n = 0; n < 2; ++n) acc[m][n] = (f32x4){0.f, 0.f, 0.f, 0.f};

#define K1_STAGE(BUF, KB)                                                      \
    gload16(asrc0 + (KB), &Abuf[BUF][(0 * 256 + w * 64) * 4]);                 \
    gload16(asrc1 + (KB), &Abuf[BUF][(1 * 256 + w * 64) * 4]);                 \
    gload16(asrc2 + (KB), &Abuf[BUF][(2 * 256 + w * 64) * 4]);                 \
    gload16(asrc3 + (KB), &Abuf[BUF][(3 * 256 + w * 64) * 4]);                 \
    gload16(bsrch + (KB), &Bhbuf[BUF][w * 512]);                               \
    gload16(bsrcl + (KB), &Blbuf[BUF][w * 512]);

#define K1_COMPUTE(BUF)                                                        \
    {                                                                          \
        short8 bh[2], bl[2];                                                   \
        _Pragma("unroll")                                                      \
        for (int n = 0; n < 2; ++n) {                                          \
            const int c  = (wn * 2 + n) * 16 + (l & 15);                       \
            const int ph = c * 4 + ((l >> 4) ^ (c & 3));                       \
            bh[n] = *(const short8*)&Bhbuf[BUF][ph * 8];                       \
            bl[n] = *(const short8*)&Blbuf[BUF][ph * 8];                       \
        }                                                                      \
        _Pragma("unroll")                                                      \
        for (int m = 0; m < 4; ++m) {                                          \
            const int row = (wm * 4 + m) * 16 + (l & 15);                      \
            const int p0  = row * 8 + (((l >> 4) * 2 + 0) ^ (row & 7));        \
            const int p1  = row * 8 + (((l >> 4) * 2 + 1) ^ (row & 7));        \
            const float4 a0 = *(const float4*)&Abuf[BUF][p0 * 4];              \
            const float4 a1 = *(const float4*)&Abuf[BUF][p1 * 4];              \
            short8 ah, al8;                                                    \
            split8(a0, a1, ah, al8);                                           \
            _Pragma("unroll")                                                  \
            for (int n = 0; n < 2; ++n) {                                      \
                acc[m][n] = __builtin_amdgcn_mfma_f32_16x16x32_bf16(ah,  bh[n], acc[m][n], 0, 0, 0); \
                acc[m][n] = __builtin_amdgcn_mfma_f32_16x16x32_bf16(ah,  bl[n], acc[m][n], 0, 0, 0); \
                acc[m][n] = __builtin_amdgcn_mfma_f32_16x16x32_bf16(al8, bh[n], acc[m][n], 0, 0, 0); \
            }                                                                  \
        }                                                                      \
    }

    K1_STAGE(0, 0);
    __syncthreads();

    for (int ti = 0; ti < KD / 32; ++ti) {       // 64 tiles
        const int buf = ti & 1;
        if (ti + 1 < KD / 32) { K1_STAGE(buf ^ 1, (ti + 1) * 32); }
        K1_COMPUTE(buf);
        __syncthreads();
    }

    // epilogue: bias + channel-major float4 stores (m89 C/D mapping)
#pragma unroll
    for (int n = 0; n < 2; ++n) {
        const int col = n0 + (wn * 2 + n) * 16 + (l & 15);
        const float b = bp[col];
#pragma unroll
        for (int m = 0; m < 4; ++m) {
            const int tok = m0 + (wm * 4 + m) * 16 + (l >> 4) * 4;
            float4 st = { acc[m][n].x + b, acc[m][n].y + b,
                          acc[m][n].z + b, acc[m][n].w + b };
            *(float4*)&hT[(size_t)col * NT + tok] = st;
        }
    }
#undef K1_STAGE
#undef K1_COMPUTE
}

// ---------------------------------------------------------------------------
// K23: fused per-head MLP + gate. Per block: 128 tokens.
//   accg = bc + sum_h bcpart[h]                  (exact fold bias)
//   for head: hid = relu(h_h @ W1_h + b1_h); accg += hid @ W2c_h
//   gl = accg / clip(T); top-2 + softmax; write gates/idx/gl.
// hlT never materialized. 256 thr; per-thread 4e x 8tok.
// ---------------------------------------------------------------------------
__global__ __launch_bounds__(256) void k23_gate(const float* __restrict__ hT,
                                                const float* __restrict__ W1,
                                                const float* __restrict__ b1,
                                                const float* __restrict__ W2c,
                                                const float* __restrict__ bcpart,
                                                const float* __restrict__ bc,
                                                const float* __restrict__ temp,
                                                float* __restrict__ out)
{
    __shared__ float W1s[64][64];
    __shared__ float W2cs[64][64];
    __shared__ float Hs[64][132];

    const int t    = threadIdx.x;
    const int eg   = t & 15;          // e = eg*4 + j
    const int tg   = t >> 4;          // tok = tok0 + tg*8 + i
    const int tok0 = blockIdx.x * 128;

    const float tv  = fminf(fmaxf(temp[0], 0.5f), 5.0f);
    const float inv = 1.0f / tv;

    float accg[4][8];
    {
        float bcp[4];
#pragma unroll
        for (int j = 0; j < 4; ++j) {
            const int e = eg * 4 + j;
            bcp[j] = bc[e] + bcpart[e] + bcpart[NE + e]
                   + bcpart[2 * NE + e] + bcpart[3 * NE + e];
        }
#pragma unroll
        for (int j = 0; j < 4; ++j)
#pragma unroll
            for (int i = 0; i < 8; ++i) accg[j][i] = bcp[j];
    }

    for (int head = 0; head < NH; ++head) {
        __syncthreads();   // prior head's W2cs/Hs reads complete
        {   // stage W1[head], W2c[head]
            const float4* g1 = (const float4*)(W1 + (size_t)head * HD * HD);
            const float4* g2 = (const float4*)(W2c + (size_t)head * HD * HD);
            float4* s1 = (float4*)&W1s[0][0];
            float4* s2 = (float4*)&W2cs[0][0];
#pragma unroll
            for (int q = 0; q < 4; ++q) {
                s1[t + q * 256] = g1[t + q * 256];
                s2[t + q * 256] = g2[t + q * 256];
            }
        }
        const float4 b1v = *(const float4*)&b1[head * HD + eg * 4];
        __syncthreads();

        // stage 1: hid = relu(b1 + h @ W1)
        float acc[4][8];
        {
            const float bb[4] = { b1v.x, b1v.y, b1v.z, b1v.w };
#pragma unroll
            for (int j = 0; j < 4; ++j)
#pragma unroll
                for (int i = 0; i < 8; ++i) acc[j][i] = bb[j];
        }
        const float* hbase = &hT[(size_t)(head * HD) * NT + tok0 + tg * 8];
#pragma unroll 4
        for (int d = 0; d < HD; ++d) {
            const float4 w  = *(const float4*)&W1s[d][eg * 4];
            const float4 h0 = *(const float4*)&hbase[(size_t)d * NT];
            const float4 h1 = *(const float4*)&hbase[(size_t)d * NT + 4];
            const float wv[4] = { w.x, w.y, w.z, w.w };
            const float hv[8] = { h0.x, h0.y, h0.z, h0.w, h1.x, h1.y, h1.z, h1.w };
#pragma unroll
            for (int j = 0; j < 4; ++j)
#pragma unroll
                for (int i = 0; i < 8; ++i)
                    acc[j][i] = fmaf(wv[j], hv[i], acc[j][i]);
        }
#pragma unroll
        for (int j = 0; j < 4; ++j) {
            float4 lo, hi;
            lo.x = fmaxf(acc[j][0], 0.f); lo.y = fmaxf(acc[j][1], 0.f);
            lo.z = fmaxf(acc[j][2], 0.f); lo.w = fmaxf(acc[j][3], 0.f);
            hi.x = fmaxf(acc[j][4], 0.f); hi.y = fmaxf(acc[j][5], 0.f);
            hi.z = fmaxf(acc[j][6], 0.f); hi.w = fmaxf(acc[j][7], 0.f);
            *(float4*)&Hs[eg * 4 + j][tg * 8]     = lo;
            *(float4*)&Hs[eg * 4 + j][tg * 8 + 4] = hi;
        }
        __syncthreads();

        // stage 2: accg += Hs @ W2c[head]
#pragma unroll 4
        for (int d = 0; d < HD; ++d) {
            const float4 w  = *(const float4*)&W2cs[d][eg * 4];
            const float4 h0 = *(const float4*)&Hs[d][tg * 8];
            const float4 h1 = *(const float4*)&Hs[d][tg * 8 + 4];
            const float wv[4] = { w.x, w.y, w.z, w.w };
            const float hv[8] = { h0.x, h0.y, h0.z, h0.w, h1.x, h1.y, h1.z, h1.w };
#pragma unroll
            for (int j = 0; j < 4; ++j)
#pragma unroll
                for (int i = 0; i < 8; ++i)
                    accg[j][i] = fmaf(wv[j], hv[i], accg[j][i]);
        }
    }

    // top-2 + softmax + outputs, per token i
#pragma unroll
    for (int i = 0; i < 8; ++i) {
        const int tok = tok0 + tg * 8 + i;
        float gl_[4];
#pragma unroll
        for (int j = 0; j < 4; ++j) gl_[j] = accg[j][i] * inv;

        float v1 = gl_[0]; int i1 = eg * 4;
#pragma unroll
        for (int j = 1; j < 4; ++j)
            if (gl_[j] > v1) { v1 = gl_[j]; i1 = eg * 4 + j; }
#pragma unroll
        for (int off = 8; off >= 1; off >>= 1) {
            const float ov = __shfl_xor(v1, off);
            const int   oi = __shfl_xor(i1, off);
            if (ov > v1 || (ov == v1 && oi < i1)) { v1 = ov; i1 = oi; }
        }
        float v2 = -INFINITY; int i2 = NE;
#pragma unroll
        for (int j = 0; j < 4; ++j) {
            const int e = eg * 4 + j;
            if (e != i1 && gl_[j] > v2) { v2 = gl_[j]; i2 = e; }
        }
#pragma unroll
        for (int off = 8; off >= 1; off >>= 1) {
            const float ov = __shfl_xor(v2, off);
            const int   oi = __shfl_xor(i2, off);
            if (ov > v2 || (ov == v2 && oi < i2)) { v2 = ov; i2 = oi; }
        }

        const float e2  = expf(v2 - v1);
        const float s   = 1.f + e2;
        const float g1v = 1.f / s;
        const float g2v = e2 / s;

        float4 gv;
        {
            const int e0 = eg * 4;
            gv.x = (e0 + 0 == i1) ? g1v : ((e0 + 0 == i2) ? g2v : 0.f);
            gv.y = (e0 + 1 == i1) ? g1v : ((e0 + 1 == i2) ? g2v : 0.f);
            gv.z = (e0 + 2 == i1) ? g1v : ((e0 + 2 == i2) ? g2v : 0.f);
            gv.w = (e0 + 3 == i1) ? g1v : ((e0 + 3 == i2) ? g2v : 0.f);
        }
        *(float4*)&out[GATES_OFF + (size_t)tok * NE + eg * 4] = gv;
        const float4 glv = { gl_[0], gl_[1], gl_[2], gl_[3] };
        *(float4*)&out[GL_OFF + (size_t)tok * NE + eg * 4] = glv;
        if (eg == 0) {
            out[IDX_OFF + (size_t)tok * 2 + 0] = (float)i1;
            out[IDX_OFF + (size_t)tok * 2 + 1] = (float)i2;
        }
    }
}

// ---------------------------------------------------------------------------
extern "C" void kernel_launch(void* const* d_in, const int* in_sizes, int n_in,
                              void* d_out, int out_size, void* d_ws, size_t ws_size,
                              hipStream_t stream)
{
    (void)in_sizes; (void)n_in; (void)out_size; (void)ws_size;

    const float* x    = (const float*)d_in[0];
    const float* Wp   = (const float*)d_in[1];
    const float* bp   = (const float*)d_in[2];
    const float* W1   = (const float*)d_in[3];
    const float* b1   = (const float*)d_in[4];
    const float* W2   = (const float*)d_in[5];
    const float* b2   = (const float*)d_in[6];
    const float* Wc   = (const float*)d_in[7];
    const float* bc   = (const float*)d_in[8];
    const float* temp = (const float*)d_in[9];

    float* out = (float*)d_out;
    float* hT  = (float*)d_ws;                         // 16.8 MB
    ushort* WpT_hi = (ushort*)(hT + (size_t)PROJ * NT); // 1 MB
    ushort* WpT_lo = WpT_hi + (size_t)KD * PROJ;        // 1 MB
    float*  W2c    = (float*)(WpT_lo + (size_t)KD * PROJ); // 64 KB
    float*  bcpart = W2c + NH * HD * NE;                // 1 KB

    k0_split<<<dim3(KD / 64, PROJ / 64), 256, 0, stream>>>(Wp, WpT_hi, WpT_lo);
    k0c     <<<dim3(NH),                 256, 0, stream>>>(W2, Wc, b2, W2c, bcpart);
    k1_mfma <<<dim3(PROJ / 64, NT / 128), 256, 0, stream>>>(x, WpT_hi, WpT_lo, bp, hT);
    k23_gate<<<dim3(NT / 128),           256, 0, stream>>>(hT, W1, b1, W2c, bcpart, bc, temp, out);
}